// Round 17
// baseline (1079.164 us; speedup 1.0000x reference)
//
#include <hip/hip_runtime.h>
#include <math.h>

#define BATCH    512
#define T_PAST_  360
#define T_FUT_   1800
#define FUT_SEQ  50
#define WSPF_    34
#define T_TOT    2060
#define T_PAD    2176                 // 2060 padded (zero tail) for guard-free prefetch
#define H_SZ     64
#define EPB      16                   // batch elements per block (MFMA N)
#define NGRP     (BATCH / EPB)        // 32 blocks
#define LOG2E    1.44269504f
#define N2LOG2E  (-2.885390082f)

typedef __fp16 f16x8 __attribute__((ext_vector_type(8)));
typedef __fp16 h2v   __attribute__((ext_vector_type(2)));
typedef float  f32x4 __attribute__((ext_vector_type(4)));

__device__ __forceinline__ int   as_i(h2v v)   { return __builtin_bit_cast(int, v); }
__device__ __forceinline__ f16x8 as_f8(int4 v) { return __builtin_bit_cast(f16x8, v); }
__device__ __forceinline__ float rcp_(float x) { return __builtin_amdgcn_rcpf(x); }
__device__ __forceinline__ float exp2_(float x){ return __builtin_amdgcn_exp2f(x); }

__device__ __forceinline__ float dot2_(int a, int b, float c) {
#if __has_builtin(__builtin_amdgcn_fdot2)
    return __builtin_amdgcn_fdot2(__builtin_bit_cast(h2v, a),
                                  __builtin_bit_cast(h2v, b), c, false);
#else
    h2v av = __builtin_bit_cast(h2v, a), bv = __builtin_bit_cast(h2v, b);
    return fmaf((float)av.x, (float)bv.x, fmaf((float)av.y, (float)bv.y, c));
#endif
}

// ---- kernel 1: pack x = [x0,x1] [x2,1] fp16 words into d_ws, layout [g][t][n] ----
__global__ __launch_bounds__(256)
void pack_x_kernel(const float* __restrict__ wi, const float* __restrict__ wf,
                   int2* __restrict__ xp) {
    int idx = blockIdx.x * 256 + threadIdx.x;     // = (g*T_PAD + t)*16 + n
    if (idx >= NGRP * T_PAD * EPB) return;
    int n = idx & 15;
    int t = (idx >> 4) % T_PAD;
    int g = idx / (16 * T_PAD);
    int b = g * EPB + n;
    float x0 = 0.f, x1 = 0.f, x2 = 0.f;
    if (t < T_PAST_) {
        const float* p = wi + ((size_t)b * T_PAST_ + t) * 3;
        x0 = p[0]; x1 = p[1]; x2 = p[2];
    } else if (t < T_TOT) {
        const float* p = wf + ((size_t)b * T_FUT_ + (t - T_PAST_)) * 3;
        x0 = p[0]; x1 = p[1]; x2 = p[2];
    }
    int2 v;
    v.x = as_i(__builtin_amdgcn_cvt_pkrtz(x0, x1));
    v.y = as_i(__builtin_amdgcn_cvt_pkrtz(x2, 1.0f));
    xp[idx] = v;
}

// ---- kernel 2: the recurrence. 32 blocks x 1024 threads (16 waves). ----
// Wave w = MFMA row-tile T=w. Per step: 2 chained mfma_f32_16x16x32_f16
// compute all 256x16 gate pre-activations; A rows are ordered so C reg j =
// gate j of unit u=4w+(lane>>4), elem n=lane&15 -> in-lane activations and
// c/h update, no cross-lane gather. h goes through one small LDS buffer with
// a k-slot permutation p(u) so next step's B-frags are 2 contiguous
// ds_read_b128. A and B use the SAME k-slot labeling, so the contraction is
// correct regardless of the hardware's internal k mapping (bijection cancels).
__global__ __launch_bounds__(1024, 1)
void lstm_mfma_kernel(const float* __restrict__ W_ih, const float* __restrict__ W_hh,
                      const float* __restrict__ b_ih, const float* __restrict__ b_hh,
                      const int2* __restrict__ xp, float* __restrict__ out) {
    __shared__ __fp16 hP[2][EPB][72];   // [buf][elem n][permuted k], pad 72

    const int tid  = threadIdx.x;
    const int w    = tid >> 6;          // wave / row-tile
    const int lane = tid & 63;
    const int n    = lane & 15;         // elem within group (MFMA col)
    const int kg   = lane >> 4;         // k-group (B) / unit-sub q (C)
    const int blk  = blockIdx.x;

    for (int i = tid; i < 2 * EPB * 72; i += 1024)
        ((__fp16*)hP)[i] = (__fp16)0.f;                    // h(0) = 0

    // ---- A-frags: A row (lane&15) = tile-row 4*q_a + r  -> gate r, unit 4w+q_a
    const int tr   = lane & 15;
    const int q_a  = tr >> 2, r = tr & 3;
    const int arow = r * H_SZ + 4 * w + q_a;
    const float s_r = ((r == 2) ? 2.f : 1.f) * LOG2E;      // tanh fold + exp2 fold
    f16x8 A0, A1;
    #pragma unroll
    for (int j = 0; j < 8; ++j) {
        int k = 4 * kg + (j & 3) + 16 * (j >> 2);          // shared k-slot labeling
        A0[j] = (__fp16)(W_hh[(size_t)arow * H_SZ + k]      * s_r);
        A1[j] = (__fp16)(W_hh[(size_t)arow * H_SZ + 32 + k] * s_r);
    }

    // ---- C-side role: this lane owns all 4 gates of unit u, elem n ----
    const int u = 4 * w + kg;
    int wih01[4], wih2b[4];
    #pragma unroll
    for (int j = 0; j < 4; ++j) {
        const float sj = ((j == 2) ? 2.f : 1.f) * LOG2E;
        int rowj = j * H_SZ + u;
        wih01[j] = as_i(__builtin_amdgcn_cvt_pkrtz(W_ih[rowj*3+0]*sj, W_ih[rowj*3+1]*sj));
        wih2b[j] = as_i(__builtin_amdgcn_cvt_pkrtz(W_ih[rowj*3+2]*sj,
                                                   (b_ih[rowj] + b_hh[rowj])*sj));
    }
    // write position: inverse of the B-frag k-slot labeling
    const int p_u = 32*(u>>5) + 8*((u>>2)&3) + (u&3) + 4*((u>>4)&1);

    const int2* xrow = xp + (size_t)blk * T_PAD * EPB;
    __fp16* outh = (__fp16*)out;        // checkpoint h stash: first 128B of each token

    float c = 0.f;
    int next_cp = T_PAST_ + WSPF_ - 1;
    int cp_k = 0;
    int2 xw = xrow[0 * EPB + n];

    __syncthreads();

#define STEP(SRC, DST, T_) {                                                   \
        int4 braw0 = *(const int4*)&hP[SRC][n][8 * kg];                        \
        int4 braw1 = *(const int4*)&hP[SRC][n][32 + 8 * kg];                   \
        int2 xn = xrow[(T_ + 1) * EPB + n];            /* prefetch next x */   \
        float xb0 = dot2_(wih2b[0], xw.y, dot2_(wih01[0], xw.x, 0.f));         \
        float xb1 = dot2_(wih2b[1], xw.y, dot2_(wih01[1], xw.x, 0.f));         \
        float xb2 = dot2_(wih2b[2], xw.y, dot2_(wih01[2], xw.x, 0.f));         \
        float xb3 = dot2_(wih2b[3], xw.y, dot2_(wih01[3], xw.x, 0.f));         \
        f32x4 acc = {0.f, 0.f, 0.f, 0.f};                                      \
        acc = __builtin_amdgcn_mfma_f32_16x16x32_f16(A0, as_f8(braw0), acc, 0, 0, 0); \
        acc = __builtin_amdgcn_mfma_f32_16x16x32_f16(A1, as_f8(braw1), acc, 0, 0, 0); \
        float gi = rcp_(1.f + exp2_(-(acc[0] + xb0)));                         \
        float gf = rcp_(1.f + exp2_(-(acc[1] + xb1)));                         \
        float gg = fmaf(2.f, rcp_(1.f + exp2_(-(acc[2] + xb2))), -1.f);        \
        float go = rcp_(1.f + exp2_(-(acc[3] + xb3)));                         \
        c = fmaf(gf, c, gi * gg);                                              \
        float th = fmaf(2.f, rcp_(1.f + exp2_(c * N2LOG2E)), -1.f);            \
        float h = go * th;                                                     \
        hP[DST][n][p_u] = (__fp16)h;                                           \
        if (T_ == next_cp) {                                                   \
            outh[((size_t)(blk * EPB + n) * FUT_SEQ + cp_k) * 128 + u] = (__fp16)h; \
            next_cp += WSPF_; ++cp_k;                                          \
        }                                                                      \
        xw = xn;                                                               \
        __syncthreads();                                                       \
    }

    for (int t = 0; t < T_TOT; t += 2) {
        STEP(0, 1, t)
        STEP(1, 0, t + 1)
    }
#undef STEP
}

// ---- kernel 3: projection. One wave per (b,cp) token; reads the fp16 h
// stash from out (in-wave, before overwriting), writes the f32 projection. ----
__global__ __launch_bounds__(64)
void proj_kernel(const float* __restrict__ W_proj, const float* __restrict__ b_proj,
                 float* __restrict__ out) {
    __shared__ int hs[32];
    const int bcp = blockIdx.x;
    const int j   = threadIdx.x;
    if (j < 32) hs[j] = ((const int*)out)[(size_t)bcp * 64 + j];
    __syncthreads();                    // single wave: cheap, orders LDS
    const float* wr = W_proj + j * H_SZ;
    float p = b_proj[j];
    #pragma unroll 8
    for (int m = 0; m < 32; ++m) {
        h2v hv = __builtin_bit_cast(h2v, hs[m]);
        p = fmaf(wr[2*m], (float)hv.x, fmaf(wr[2*m+1], (float)hv.y, p));
    }
    out[(size_t)bcp * 64 + j] = p;
}

extern "C" void kernel_launch(void* const* d_in, const int* in_sizes, int n_in,
                              void* d_out, int out_size, void* d_ws, size_t ws_size,
                              hipStream_t stream) {
    const float* wave_input  = (const float*)d_in[0];
    const float* wave_future = (const float*)d_in[1];
    const float* W_ih        = (const float*)d_in[2];
    const float* W_hh        = (const float*)d_in[3];
    const float* b_ih        = (const float*)d_in[4];
    const float* b_hh        = (const float*)d_in[5];
    const float* W_proj      = (const float*)d_in[6];
    const float* b_proj      = (const float*)d_in[7];
    float* out               = (float*)d_out;

    int2* xp = (int2*)d_ws;             // needs NGRP*T_PAD*EPB*8 = 8.9 MB

    pack_x_kernel<<<(NGRP * T_PAD * EPB + 255) / 256, 256, 0, stream>>>(
        wave_input, wave_future, xp);
    lstm_mfma_kernel<<<NGRP, 1024, 0, stream>>>(
        W_ih, W_hh, b_ih, b_hh, xp, out);
    proj_kernel<<<BATCH * FUT_SEQ, 64, 0, stream>>>(W_proj, b_proj, out);
}